// Round 5
// baseline (6863.318 us; speedup 1.0000x reference)
//
#include <hip/hip_runtime.h>
#include <hip/hip_bf16.h>
#include <math.h>

#define NN 50000
#define TT 12
#define FF 32
#define HH 64

static inline size_t align256(size_t x){ return (x + 255) & ~(size_t)255; }

// ---------------- graph preprocessing ----------------

__global__ void k_count(const int* __restrict__ dst, int E, int* __restrict__ cnt){
  int i = blockIdx.x*blockDim.x + threadIdx.x;
  if (i < E) atomicAdd(&cnt[dst[i]], 1);
}

__global__ void k_dinv(const int* __restrict__ cnt, float* __restrict__ dinv,
                       float* __restrict__ invd, int n){
  int i = blockIdx.x*blockDim.x + threadIdx.x;
  if (i < n){
    float d = (float)(cnt[i] + 1);            // +1 self loop
    dinv[i] = (float)(1.0 / sqrt((double)d));
    invd[i] = 1.0f / d;
  }
}

#define SCAN_T 256
__global__ void k_scan(const int* __restrict__ cnt, int* __restrict__ rp, int n){
  __shared__ int s[SCAN_T];
  int t = threadIdx.x;
  int chunk = (n + SCAN_T - 1) / SCAN_T;
  int lo = t*chunk, hi = min(lo+chunk, n);
  int sum = 0;
  for (int i = lo; i < hi; ++i) sum += cnt[i];
  s[t] = sum; __syncthreads();
  for (int off = 1; off < SCAN_T; off <<= 1){
    int v = (t >= off) ? s[t-off] : 0;
    __syncthreads();
    s[t] += v;
    __syncthreads();
  }
  int run = (t == 0) ? 0 : s[t-1];
  for (int i = lo; i < hi; ++i){ rp[i] = run; run += cnt[i]; }
  if (t == SCAN_T-1) rp[n] = run;
}

__global__ void k_fill(const int* __restrict__ src, const int* __restrict__ dst, int E,
                       const int* __restrict__ rp, int* __restrict__ cur,
                       const float* __restrict__ dinv,
                       int* __restrict__ es, float* __restrict__ en){
  int i = blockIdx.x*blockDim.x + threadIdx.x;
  if (i < E){
    int d = dst[i], s = src[i];
    int pos = rp[d] + atomicAdd(&cur[d], 1);
    es[pos] = s;
    en[pos] = dinv[s] * dinv[d];
  }
}

// ---------------- aggregation (SpMM), single timestep ----------------
// xt: [N,32]. Half-wave (32 lanes) per node; lane&31 = feature.
__global__ void k_agg_x(const float* __restrict__ xt, const int* __restrict__ rp,
                        const int* __restrict__ es, const float* __restrict__ en,
                        const float* __restrict__ invd, float* __restrict__ out){
  int n = (blockIdx.x*blockDim.x + threadIdx.x) >> 5;
  if (n >= NN) return;
  int f = threadIdx.x & 31;
  float acc = invd[n] * xt[(size_t)n*FF + f];
  int e = rp[n], e1 = rp[n+1];
  for (; e + 4 <= e1; e += 4){
    int   s0 = es[e],   s1 = es[e+1], s2 = es[e+2], s3 = es[e+3];
    float w0 = en[e],   w1 = en[e+1], w2 = en[e+2], w3 = en[e+3];
    float v0 = xt[(size_t)s0*FF + f];
    float v1 = xt[(size_t)s1*FF + f];
    float v2 = xt[(size_t)s2*FF + f];
    float v3 = xt[(size_t)s3*FF + f];
    acc += w0*v0; acc += w1*v1; acc += w2*v2; acc += w3*v3;
  }
  for (; e < e1; ++e) acc += en[e] * xt[(size_t)es[e]*FF + f];
  out[(size_t)n*FF + f] = acc;
}

// h: [N,64]. Wave per node; lane = feature.
__global__ void k_agg_h(const float* __restrict__ h, const int* __restrict__ rp,
                        const int* __restrict__ es, const float* __restrict__ en,
                        const float* __restrict__ invd, float* __restrict__ out){
  int n = blockIdx.x*(blockDim.x >> 6) + (threadIdx.x >> 6);
  if (n >= NN) return;
  int lane = threadIdx.x & 63;
  float acc = invd[n] * h[(size_t)n*HH + lane];
  int e = rp[n], e1 = rp[n+1];
  for (; e + 4 <= e1; e += 4){
    int   s0 = es[e],   s1 = es[e+1], s2 = es[e+2], s3 = es[e+3];
    float w0 = en[e],   w1 = en[e+1], w2 = en[e+2], w3 = en[e+3];
    float v0 = h[(size_t)s0*HH + lane];
    float v1 = h[(size_t)s1*HH + lane];
    float v2 = h[(size_t)s2*HH + lane];
    float v3 = h[(size_t)s3*HH + lane];
    acc += w0*v0; acc += w1*v1; acc += w2*v2; acc += w3*v3;
  }
  for (; e < e1; ++e) acc += en[e] * h[(size_t)es[e]*HH + lane];
  out[(size_t)n*HH + lane] = acc;
}

// ---------------- GEMM: C[M,64] = act(A[M,K] @ W[K,64] + bias) --------------
template<int K, int ROWS, bool RELU>
__launch_bounds__(64)
__global__ void k_gemm(const float* __restrict__ A, const float* __restrict__ W,
                       const float* __restrict__ bias, float* __restrict__ C,
                       int M){
  int col = threadIdx.x;
  float w[K];
  #pragma unroll
  for (int k = 0; k < K; ++k) w[k] = W[(size_t)k*HH + col];
  float b = bias[col];
  int row0 = blockIdx.x*ROWS;
  if (row0 >= M) return;
  float acc[ROWS];
  #pragma unroll
  for (int r = 0; r < ROWS; ++r) acc[r] = b;
  #pragma unroll
  for (int r = 0; r < ROWS; ++r){
    const float* ar = A + (size_t)(row0 + r)*K;
    #pragma unroll
    for (int k = 0; k < K; ++k)
      acc[r] = fmaf(ar[k], w[k], acc[r]);
  }
  #pragma unroll
  for (int r = 0; r < ROWS; ++r){
    float v = acc[r];
    if (RELU) v = fmaxf(v, 0.f);
    C[(size_t)(row0 + r)*HH + col] = v;
  }
}

// ---------------- fully fused GRU step --------------------------------------
// Block = 2 waves. lane = output column j. Wave 0: input side (h2 @ W_ih^T),
// wave 1: hidden side (hprev @ W_hh^T). 3 gate weight rows per lane in VGPRs
// (loaded once per block); grid-stride over 8-node tiles; h rows staged in LDS
// and read via same-address broadcast; gate halves exchanged through LDS.
#define GRB 8
__launch_bounds__(128, 2)
__global__ void k_gruf(const float* __restrict__ h2, const float* __restrict__ hprev,
                       const float* __restrict__ Wih, const float* __restrict__ Whh,
                       const float* __restrict__ bih, const float* __restrict__ bhh,
                       float* __restrict__ hnew, int ntiles){
  __shared__ float sh[2][GRB][64];     // [0]=h2 rows, [1]=hprev rows (4 KB)
  __shared__ float exi[4][3][64];      // input-side rows 4..7 (from wave 0)
  __shared__ float exh[4][3][64];      // hidden-side rows 0..3 (from wave 1)
  int tid = threadIdx.x, wv = tid >> 6, lane = tid & 63;
  const float* Wsel = wv ? Whh : Wih;
  float w0[64], w1[64], w2[64];
  {
    const float* p0 = Wsel + (size_t)lane*64;
    const float* p1 = Wsel + (size_t)(64 + lane)*64;
    const float* p2 = Wsel + (size_t)(128 + lane)*64;
    #pragma unroll
    for (int k = 0; k < 64; k += 4){
      float4 a = *(const float4*)(p0 + k);
      float4 b = *(const float4*)(p1 + k);
      float4 c = *(const float4*)(p2 + k);
      w0[k]=a.x; w0[k+1]=a.y; w0[k+2]=a.z; w0[k+3]=a.w;
      w1[k]=b.x; w1[k+1]=b.y; w1[k+2]=b.z; w1[k+3]=b.w;
      w2[k]=c.x; w2[k+1]=c.y; w2[k+2]=c.z; w2[k+3]=c.w;
    }
  }
  float bi0 = bih[lane], bi1 = bih[64+lane], bi2 = bih[128+lane];
  float bh0 = bhh[lane], bh1 = bhh[64+lane], bh2 = bhh[128+lane];

  for (int tile = blockIdx.x; tile < ntiles; tile += gridDim.x){
    int n0 = tile * GRB;
    __syncthreads();   // sh/ex free from previous tile
    ((float4*)sh)[tid]       = ((const float4*)(h2    + (size_t)n0*64))[tid];
    ((float4*)sh)[128 + tid] = ((const float4*)(hprev + (size_t)n0*64))[tid];
    __syncthreads();

    float a0[GRB], a1[GRB], a2[GRB];
    #pragma unroll
    for (int r = 0; r < GRB; ++r){ a0[r]=0.f; a1[r]=0.f; a2[r]=0.f; }
    #pragma unroll
    for (int r = 0; r < GRB; ++r){
      const float* hk = &sh[wv][r][0];
      #pragma unroll
      for (int k = 0; k < 64; k += 4){
        float4 v = *(const float4*)(hk + k);   // LDS broadcast (same addr)
        a0[r] = fmaf(v.x, w0[k],   a0[r]);
        a1[r] = fmaf(v.x, w1[k],   a1[r]);
        a2[r] = fmaf(v.x, w2[k],   a2[r]);
        a0[r] = fmaf(v.y, w0[k+1], a0[r]);
        a1[r] = fmaf(v.y, w1[k+1], a1[r]);
        a2[r] = fmaf(v.y, w2[k+1], a2[r]);
        a0[r] = fmaf(v.z, w0[k+2], a0[r]);
        a1[r] = fmaf(v.z, w1[k+2], a1[r]);
        a2[r] = fmaf(v.z, w2[k+2], a2[r]);
        a0[r] = fmaf(v.w, w0[k+3], a0[r]);
        a1[r] = fmaf(v.w, w1[k+3], a1[r]);
        a2[r] = fmaf(v.w, w2[k+3], a2[r]);
      }
    }
    // exchange the half each wave does NOT finalize
    if (wv == 0){
      #pragma unroll
      for (int r = 0; r < 4; ++r){
        exi[r][0][lane] = a0[4+r]; exi[r][1][lane] = a1[4+r]; exi[r][2][lane] = a2[4+r];
      }
    } else {
      #pragma unroll
      for (int r = 0; r < 4; ++r){
        exh[r][0][lane] = a0[r]; exh[r][1][lane] = a1[r]; exh[r][2][lane] = a2[r];
      }
    }
    __syncthreads();
    // epilogue: wave 0 -> rows 0..3, wave 1 -> rows 4..7
    #pragma unroll
    for (int r = 0; r < 4; ++r){
      int row = wv ? (4 + r) : r;
      float ir, iz, in_, hr, hz, hn;
      if (wv == 0){
        ir = a0[r]; iz = a1[r]; in_ = a2[r];
        hr = exh[r][0][lane]; hz = exh[r][1][lane]; hn = exh[r][2][lane];
      } else {
        hr = a0[4+r]; hz = a1[4+r]; hn = a2[4+r];
        ir = exi[r][0][lane]; iz = exi[r][1][lane]; in_ = exi[r][2][lane];
      }
      ir += bi0; iz += bi1; in_ += bi2;
      hr += bh0; hz += bh1; hn += bh2;
      float rg = 1.f/(1.f + expf(-(ir + hr)));
      float zg = 1.f/(1.f + expf(-(iz + hz)));
      float nv = tanhf(in_ + rg*hn);
      float hp = sh[1][row][lane];
      hnew[(size_t)(n0 + row)*64 + lane] = (1.f - zg)*nv + zg*hp;
    }
  }
}

// ---------------- head: logits = relu(h@Wc1+bc1)@Wc2 + bc2 ----------------
__global__ void k_head(const float* __restrict__ h, const float* __restrict__ Wc1,
                       const float* __restrict__ bc1, const float* __restrict__ Wc2,
                       const float* __restrict__ bc2, float* __restrict__ out){
  __shared__ float w1[64*32];
  __shared__ float w2[32];
  for (int i = threadIdx.x; i < 64*32; i += blockDim.x) w1[i] = Wc1[i];
  if (threadIdx.x < 32) w2[threadIdx.x] = Wc2[threadIdx.x];
  __syncthreads();
  int n = blockIdx.x*blockDim.x + threadIdx.x;
  if (n >= NN) return;
  const float* hr = h + (size_t)n*64;
  float hreg[64];
  #pragma unroll
  for (int k = 0; k < 64; ++k) hreg[k] = hr[k];
  float acc2 = bc2[0];
  #pragma unroll
  for (int c = 0; c < 32; ++c){
    float a = bc1[c];
    #pragma unroll
    for (int k = 0; k < 64; ++k) a = fmaf(hreg[k], w1[k*32 + c], a);
    a = fmaxf(a, 0.f);
    acc2 = fmaf(a, w2[c], acc2);
  }
  out[n] = acc2;
}

// ---------------- launch ----------------
extern "C" void kernel_launch(void* const* d_in, const int* in_sizes, int n_in,
                              void* d_out, int out_size, void* d_ws, size_t ws_size,
                              hipStream_t stream){
  const float* x    = (const float*)d_in[0];
  const int*   ei   = (const int*)  d_in[1];
  const float* W1   = (const float*)d_in[2];
  const float* b1   = (const float*)d_in[3];
  const float* W2   = (const float*)d_in[4];
  const float* b2   = (const float*)d_in[5];
  const float* W_ih = (const float*)d_in[6];
  const float* W_hh = (const float*)d_in[7];
  const float* b_ih = (const float*)d_in[8];
  const float* b_hh = (const float*)d_in[9];
  const float* Wc1  = (const float*)d_in[10];
  const float* bc1  = (const float*)d_in[11];
  const float* Wc2  = (const float*)d_in[12];
  const float* bc2  = (const float*)d_in[13];
  int E = in_sizes[1] / 2;
  const int* src = ei;
  const int* dst = ei + E;

  char* w = (char*)d_ws;
  auto alloc = [&](size_t bytes){ char* p = w; w += align256(bytes); return p; };
  int*   cnt  = (int*)  alloc((size_t)NN*4);
  int*   rp   = (int*)  alloc((size_t)(NN+1)*4);
  int*   cur  = (int*)  alloc((size_t)NN*4);
  float* dinv = (float*)alloc((size_t)NN*4);
  float* invd = (float*)alloc((size_t)NN*4);
  int*   es   = (int*)  alloc((size_t)E*4);
  float* en   = (float*)alloc((size_t)E*4);
  float* U1   = (float*)alloc((size_t)NN*HH*4);   // aggX [N,32] / agg2 [N,64]
  float* U2   = (float*)alloc((size_t)NN*HH*4);   // h1 / h2  [N,64]
  float* hA   = (float*)alloc((size_t)NN*HH*4);
  float* hB   = (float*)alloc((size_t)NN*HH*4);
  if ((size_t)(w - (char*)d_ws) > ws_size) return;   // clean diagnostic fail

  hipMemsetAsync(cnt, 0, (size_t)NN*4, stream);
  hipMemsetAsync(cur, 0, (size_t)NN*4, stream);
  hipMemsetAsync(hA,  0, (size_t)NN*HH*4, stream);   // h0 = 0

  k_count<<<(E+255)/256, 256, 0, stream>>>(dst, E, cnt);
  k_dinv <<<(NN+255)/256, 256, 0, stream>>>(cnt, dinv, invd, NN);
  k_scan <<<1, SCAN_T, 0, stream>>>(cnt, rp, NN);
  k_fill <<<(E+255)/256, 256, 0, stream>>>(src, dst, E, rp, cur, dinv, es, en);

  float* hprev = hA;
  float* hnext = hB;
  for (int t = 0; t < TT; ++t){
    const float* xt = x + (size_t)t*NN*FF;
    // layer 1: aggregate x first ((A X) W == A (X W)), then GEMM 32->64 + relu
    k_agg_x<<<(NN*32 + 255)/256, 256, 0, stream>>>(xt, rp, es, en, invd, U1);
    k_gemm<FF, 16, true><<<(NN + 15)/16, 64, 0, stream>>>(U1, W1, b1, U2, NN);
    // layer 2
    k_agg_h<<<(NN + 3)/4, 256, 0, stream>>>(U2, rp, es, en, invd, U1);
    k_gemm<HH, 16, true><<<(NN + 15)/16, 64, 0, stream>>>(U1, W2, b2, U2, NN);
    // fused GRU step consuming h2 (= U2)
    k_gruf<<<2048, 128, 0, stream>>>(U2, hprev, W_ih, W_hh, b_ih, b_hh, hnext, NN/GRB);
    float* tmp = hprev; hprev = hnext; hnext = tmp;
  }

  // after 12 swaps hprev == hA
  k_head<<<(NN + 255)/256, 256, 0, stream>>>(hprev, Wc1, bc1, Wc2, bc2, (float*)d_out);
}

// Round 6
// 5049.446 us; speedup vs baseline: 1.3592x; 1.3592x over previous
//
#include <hip/hip_runtime.h>
#include <hip/hip_bf16.h>
#include <math.h>

#define NN 50000
#define TT 12
#define FF 32
#define HH 64

static inline size_t align256(size_t x){ return (x + 255) & ~(size_t)255; }

// ---------------- graph preprocessing ----------------

__global__ void k_count(const int* __restrict__ dst, int E, int* __restrict__ cnt){
  int i = blockIdx.x*blockDim.x + threadIdx.x;
  if (i < E) atomicAdd(&cnt[dst[i]], 1);
}

__global__ void k_dinv(const int* __restrict__ cnt, float* __restrict__ dinv,
                       float* __restrict__ invd, int n){
  int i = blockIdx.x*blockDim.x + threadIdx.x;
  if (i < n){
    float d = (float)(cnt[i] + 1);            // +1 self loop
    dinv[i] = (float)(1.0 / sqrt((double)d));
    invd[i] = 1.0f / d;
  }
}

#define SCAN_T 256
__global__ void k_scan(const int* __restrict__ cnt, int* __restrict__ rp, int n){
  __shared__ int s[SCAN_T];
  int t = threadIdx.x;
  int chunk = (n + SCAN_T - 1) / SCAN_T;
  int lo = t*chunk, hi = min(lo+chunk, n);
  int sum = 0;
  for (int i = lo; i < hi; ++i) sum += cnt[i];
  s[t] = sum; __syncthreads();
  for (int off = 1; off < SCAN_T; off <<= 1){
    int v = (t >= off) ? s[t-off] : 0;
    __syncthreads();
    s[t] += v;
    __syncthreads();
  }
  int run = (t == 0) ? 0 : s[t-1];
  for (int i = lo; i < hi; ++i){ rp[i] = run; run += cnt[i]; }
  if (t == SCAN_T-1) rp[n] = run;
}

__global__ void k_fill(const int* __restrict__ src, const int* __restrict__ dst, int E,
                       const int* __restrict__ rp, int* __restrict__ cur,
                       const float* __restrict__ dinv,
                       int* __restrict__ es, float* __restrict__ en){
  int i = blockIdx.x*blockDim.x + threadIdx.x;
  if (i < E){
    int d = dst[i], s = src[i];
    int pos = rp[d] + atomicAdd(&cur[d], 1);
    es[pos] = s;
    en[pos] = dinv[s] * dinv[d];
  }
}

// ---------------- aggregation (SpMM), single timestep ----------------
// xt: [N,32]. Half-wave (32 lanes) per node; lane&31 = feature.
__global__ void k_agg_x(const float* __restrict__ xt, const int* __restrict__ rp,
                        const int* __restrict__ es, const float* __restrict__ en,
                        const float* __restrict__ invd, float* __restrict__ out){
  int n = (blockIdx.x*blockDim.x + threadIdx.x) >> 5;
  if (n >= NN) return;
  int f = threadIdx.x & 31;
  float acc = invd[n] * xt[(size_t)n*FF + f];
  int e = rp[n], e1 = rp[n+1];
  for (; e + 4 <= e1; e += 4){
    int   s0 = es[e],   s1 = es[e+1], s2 = es[e+2], s3 = es[e+3];
    float w0 = en[e],   w1 = en[e+1], w2 = en[e+2], w3 = en[e+3];
    float v0 = xt[(size_t)s0*FF + f];
    float v1 = xt[(size_t)s1*FF + f];
    float v2 = xt[(size_t)s2*FF + f];
    float v3 = xt[(size_t)s3*FF + f];
    acc += w0*v0; acc += w1*v1; acc += w2*v2; acc += w3*v3;
  }
  for (; e < e1; ++e) acc += en[e] * xt[(size_t)es[e]*FF + f];
  out[(size_t)n*FF + f] = acc;
}

// h: [N,64]. Wave per node; lane = feature.
__global__ void k_agg_h(const float* __restrict__ h, const int* __restrict__ rp,
                        const int* __restrict__ es, const float* __restrict__ en,
                        const float* __restrict__ invd, float* __restrict__ out){
  int n = blockIdx.x*(blockDim.x >> 6) + (threadIdx.x >> 6);
  if (n >= NN) return;
  int lane = threadIdx.x & 63;
  float acc = invd[n] * h[(size_t)n*HH + lane];
  int e = rp[n], e1 = rp[n+1];
  for (; e + 4 <= e1; e += 4){
    int   s0 = es[e],   s1 = es[e+1], s2 = es[e+2], s3 = es[e+3];
    float w0 = en[e],   w1 = en[e+1], w2 = en[e+2], w3 = en[e+3];
    float v0 = h[(size_t)s0*HH + lane];
    float v1 = h[(size_t)s1*HH + lane];
    float v2 = h[(size_t)s2*HH + lane];
    float v3 = h[(size_t)s3*HH + lane];
    acc += w0*v0; acc += w1*v1; acc += w2*v2; acc += w3*v3;
  }
  for (; e < e1; ++e) acc += en[e] * h[(size_t)es[e]*HH + lane];
  out[(size_t)n*HH + lane] = acc;
}

// ---------------- GEMM: C[M,64] = act(A[M,K] @ W[K,64] + bias) --------------
template<int K, int ROWS, bool RELU>
__launch_bounds__(64)
__global__ void k_gemm(const float* __restrict__ A, const float* __restrict__ W,
                       const float* __restrict__ bias, float* __restrict__ C,
                       int M){
  int col = threadIdx.x;
  float w[K];
  #pragma unroll
  for (int k = 0; k < K; ++k) w[k] = W[(size_t)k*HH + col];
  float b = bias[col];
  int row0 = blockIdx.x*ROWS;
  if (row0 >= M) return;
  float acc[ROWS];
  #pragma unroll
  for (int r = 0; r < ROWS; ++r) acc[r] = b;
  #pragma unroll
  for (int r = 0; r < ROWS; ++r){
    const float* ar = A + (size_t)(row0 + r)*K;
    #pragma unroll
    for (int k = 0; k < K; ++k)
      acc[r] = fmaf(ar[k], w[k], acc[r]);
  }
  #pragma unroll
  for (int r = 0; r < ROWS; ++r){
    float v = acc[r];
    if (RELU) v = fmaxf(v, 0.f);
    C[(size_t)(row0 + r)*HH + col] = v;
  }
}

// ---------------- fused GRU step, v2 (no-spill) ------------------------------
// Block = 6 waves (384 thr). Wave wv owns ONE (side,gate): side=wv/3
// (0: h2@Wih^T, 1: hprev@Whh^T), gate=wv%3 (r,z,n). Per lane: w[64] VGPRs only.
// h rows are wave-uniform loads (scalar-broadcast). 16-node tiles; gates meet
// in a 24KB LDS exchange; epilogue flat over 384 threads.
#define GRB 16
__launch_bounds__(384, 4)
__global__ void k_gruf(const float* __restrict__ h2, const float* __restrict__ hprev,
                       const float* __restrict__ Wih, const float* __restrict__ Whh,
                       const float* __restrict__ bih, const float* __restrict__ bhh,
                       float* __restrict__ hnew, int ntiles){
  __shared__ float ex[6][GRB][64];   // 24 KB
  int tid = threadIdx.x, wv = tid >> 6, lane = tid & 63;
  int side = wv / 3;
  int gate = wv - side*3;
  const float* Wsel = side ? Whh : Wih;
  const float* hsrc = side ? hprev : h2;
  float bg = (side ? bhh : bih)[gate*64 + lane];
  float w[64];
  {
    const float* wr = Wsel + (size_t)(gate*64 + lane)*64;
    #pragma unroll
    for (int k = 0; k < 64; k += 4){
      float4 v = *(const float4*)(wr + k);
      w[k]=v.x; w[k+1]=v.y; w[k+2]=v.z; w[k+3]=v.w;
    }
  }

  for (int tile = blockIdx.x; tile < ntiles; tile += gridDim.x){
    int n0 = tile * GRB;
    float a[GRB];
    #pragma unroll
    for (int r0 = 0; r0 < GRB; r0 += 4){        // 4 independent FMA chains
      const float* h0 = hsrc + (size_t)(n0 + r0    )*64;
      const float* h1 = hsrc + (size_t)(n0 + r0 + 1)*64;
      const float* h2p= hsrc + (size_t)(n0 + r0 + 2)*64;
      const float* h3 = hsrc + (size_t)(n0 + r0 + 3)*64;
      float s0=0.f, s1=0.f, s2=0.f, s3=0.f;
      #pragma unroll
      for (int k = 0; k < 64; ++k){
        float wk = w[k];
        s0 = fmaf(h0[k],  wk, s0);
        s1 = fmaf(h1[k],  wk, s1);
        s2 = fmaf(h2p[k], wk, s2);
        s3 = fmaf(h3[k],  wk, s3);
      }
      a[r0]=s0; a[r0+1]=s1; a[r0+2]=s2; a[r0+3]=s3;
    }
    __syncthreads();                 // ex free (previous epilogue done)
    #pragma unroll
    for (int r = 0; r < GRB; ++r) ex[wv][r][lane] = a[r] + bg;
    __syncthreads();
    for (int i = tid; i < GRB*64; i += 384){
      int row = i >> 6, col = i & 63;
      float ir = ex[0][row][col], iz = ex[1][row][col], in_ = ex[2][row][col];
      float hr = ex[3][row][col], hz = ex[4][row][col], hn  = ex[5][row][col];
      float rg = 1.f/(1.f + expf(-(ir + hr)));
      float zg = 1.f/(1.f + expf(-(iz + hz)));
      float nv = tanhf(in_ + rg*hn);
      float hp = hprev[(size_t)(n0 + row)*64 + col];
      hnew[(size_t)(n0 + row)*64 + col] = (1.f - zg)*nv + zg*hp;
    }
  }
}

// ---------------- head: logits = relu(h@Wc1+bc1)@Wc2 + bc2 ----------------
__global__ void k_head(const float* __restrict__ h, const float* __restrict__ Wc1,
                       const float* __restrict__ bc1, const float* __restrict__ Wc2,
                       const float* __restrict__ bc2, float* __restrict__ out){
  __shared__ float w1[64*32];
  __shared__ float w2[32];
  for (int i = threadIdx.x; i < 64*32; i += blockDim.x) w1[i] = Wc1[i];
  if (threadIdx.x < 32) w2[threadIdx.x] = Wc2[threadIdx.x];
  __syncthreads();
  int n = blockIdx.x*blockDim.x + threadIdx.x;
  if (n >= NN) return;
  const float* hr = h + (size_t)n*64;
  float hreg[64];
  #pragma unroll
  for (int k = 0; k < 64; ++k) hreg[k] = hr[k];
  float acc2 = bc2[0];
  #pragma unroll
  for (int c = 0; c < 32; ++c){
    float a = bc1[c];
    #pragma unroll
    for (int k = 0; k < 64; ++k) a = fmaf(hreg[k], w1[k*32 + c], a);
    a = fmaxf(a, 0.f);
    acc2 = fmaf(a, w2[c], acc2);
  }
  out[n] = acc2;
}

// ---------------- launch ----------------
extern "C" void kernel_launch(void* const* d_in, const int* in_sizes, int n_in,
                              void* d_out, int out_size, void* d_ws, size_t ws_size,
                              hipStream_t stream){
  const float* x    = (const float*)d_in[0];
  const int*   ei   = (const int*)  d_in[1];
  const float* W1   = (const float*)d_in[2];
  const float* b1   = (const float*)d_in[3];
  const float* W2   = (const float*)d_in[4];
  const float* b2   = (const float*)d_in[5];
  const float* W_ih = (const float*)d_in[6];
  const float* W_hh = (const float*)d_in[7];
  const float* b_ih = (const float*)d_in[8];
  const float* b_hh = (const float*)d_in[9];
  const float* Wc1  = (const float*)d_in[10];
  const float* bc1  = (const float*)d_in[11];
  const float* Wc2  = (const float*)d_in[12];
  const float* bc2  = (const float*)d_in[13];
  int E = in_sizes[1] / 2;
  const int* src = ei;
  const int* dst = ei + E;

  char* w = (char*)d_ws;
  auto alloc = [&](size_t bytes){ char* p = w; w += align256(bytes); return p; };
  int*   cnt  = (int*)  alloc((size_t)NN*4);
  int*   rp   = (int*)  alloc((size_t)(NN+1)*4);
  int*   cur  = (int*)  alloc((size_t)NN*4);
  float* dinv = (float*)alloc((size_t)NN*4);
  float* invd = (float*)alloc((size_t)NN*4);
  int*   es   = (int*)  alloc((size_t)E*4);
  float* en   = (float*)alloc((size_t)E*4);
  float* U1   = (float*)alloc((size_t)NN*HH*4);   // aggX [N,32] / agg2 [N,64]
  float* U2   = (float*)alloc((size_t)NN*HH*4);   // h1 / h2  [N,64]
  float* hA   = (float*)alloc((size_t)NN*HH*4);
  float* hB   = (float*)alloc((size_t)NN*HH*4);
  if ((size_t)(w - (char*)d_ws) > ws_size) return;   // clean diagnostic fail

  hipMemsetAsync(cnt, 0, (size_t)NN*4, stream);
  hipMemsetAsync(cur, 0, (size_t)NN*4, stream);
  hipMemsetAsync(hA,  0, (size_t)NN*HH*4, stream);   // h0 = 0

  k_count<<<(E+255)/256, 256, 0, stream>>>(dst, E, cnt);
  k_dinv <<<(NN+255)/256, 256, 0, stream>>>(cnt, dinv, invd, NN);
  k_scan <<<1, SCAN_T, 0, stream>>>(cnt, rp, NN);
  k_fill <<<(E+255)/256, 256, 0, stream>>>(src, dst, E, rp, cur, dinv, es, en);

  float* hprev = hA;
  float* hnext = hB;
  for (int t = 0; t < TT; ++t){
    const float* xt = x + (size_t)t*NN*FF;
    // layer 1: aggregate x first ((A X) W == A (X W)), then GEMM 32->64 + relu
    k_agg_x<<<(NN*32 + 255)/256, 256, 0, stream>>>(xt, rp, es, en, invd, U1);
    k_gemm<FF, 16, true><<<(NN + 15)/16, 64, 0, stream>>>(U1, W1, b1, U2, NN);
    // layer 2
    k_agg_h<<<(NN + 3)/4, 256, 0, stream>>>(U2, rp, es, en, invd, U1);
    k_gemm<HH, 16, true><<<(NN + 15)/16, 64, 0, stream>>>(U1, W2, b2, U2, NN);
    // fused GRU step consuming h2 (= U2)
    k_gruf<<<1024, 384, 0, stream>>>(U2, hprev, W_ih, W_hh, b_ih, b_hh, hnext, NN/GRB);
    float* tmp = hprev; hprev = hnext; hnext = tmp;
  }

  // after 12 swaps hprev == hA
  k_head<<<(NN + 255)/256, 256, 0, stream>>>(hprev, Wc1, bc1, Wc2, bc2, (float*)d_out);
}

// Round 8
// 2932.529 us; speedup vs baseline: 2.3404x; 1.7219x over previous
//
#include <hip/hip_runtime.h>
#include <hip/hip_bf16.h>
#include <math.h>

#define NN 50000
#define TT 12
#define FF 32
#define HH 64

static inline size_t align256(size_t x){ return (x + 255) & ~(size_t)255; }

// ---------------- graph preprocessing ----------------

__global__ void k_count(const int* __restrict__ dst, int E, int* __restrict__ cnt){
  int i = blockIdx.x*blockDim.x + threadIdx.x;
  if (i < E) atomicAdd(&cnt[dst[i]], 1);
}

__global__ void k_dinv(const int* __restrict__ cnt, float* __restrict__ dinv,
                       float* __restrict__ invd, int n){
  int i = blockIdx.x*blockDim.x + threadIdx.x;
  if (i < n){
    float d = (float)(cnt[i] + 1);            // +1 self loop
    dinv[i] = (float)(1.0 / sqrt((double)d));
    invd[i] = 1.0f / d;
  }
}

#define SCAN_T 256
__global__ void k_scan(const int* __restrict__ cnt, int* __restrict__ rp, int n){
  __shared__ int s[SCAN_T];
  int t = threadIdx.x;
  int chunk = (n + SCAN_T - 1) / SCAN_T;
  int lo = t*chunk, hi = min(lo+chunk, n);
  int sum = 0;
  for (int i = lo; i < hi; ++i) sum += cnt[i];
  s[t] = sum; __syncthreads();
  for (int off = 1; off < SCAN_T; off <<= 1){
    int v = (t >= off) ? s[t-off] : 0;
    __syncthreads();
    s[t] += v;
    __syncthreads();
  }
  int run = (t == 0) ? 0 : s[t-1];
  for (int i = lo; i < hi; ++i){ rp[i] = run; run += cnt[i]; }
  if (t == SCAN_T-1) rp[n] = run;
}

__global__ void k_fill(const int* __restrict__ src, const int* __restrict__ dst, int E,
                       const int* __restrict__ rp, int* __restrict__ cur,
                       const float* __restrict__ dinv,
                       int* __restrict__ es, float* __restrict__ en){
  int i = blockIdx.x*blockDim.x + threadIdx.x;
  if (i < E){
    int d = dst[i], s = src[i];
    int pos = rp[d] + atomicAdd(&cur[d], 1);
    es[pos] = s;
    en[pos] = dinv[s] * dinv[d];
  }
}

// ---------------- aggregation (SpMM), single timestep ----------------
// xt: [N,32]. Half-wave (32 lanes) per node; lane&31 = feature.
__global__ void k_agg_x(const float* __restrict__ xt, const int* __restrict__ rp,
                        const int* __restrict__ es, const float* __restrict__ en,
                        const float* __restrict__ invd, float* __restrict__ out){
  int n = (blockIdx.x*blockDim.x + threadIdx.x) >> 5;
  if (n >= NN) return;
  int f = threadIdx.x & 31;
  float acc = invd[n] * xt[(size_t)n*FF + f];
  int e = rp[n], e1 = rp[n+1];
  for (; e + 4 <= e1; e += 4){
    int   s0 = es[e],   s1 = es[e+1], s2 = es[e+2], s3 = es[e+3];
    float w0 = en[e],   w1 = en[e+1], w2 = en[e+2], w3 = en[e+3];
    float v0 = xt[(size_t)s0*FF + f];
    float v1 = xt[(size_t)s1*FF + f];
    float v2 = xt[(size_t)s2*FF + f];
    float v3 = xt[(size_t)s3*FF + f];
    acc += w0*v0; acc += w1*v1; acc += w2*v2; acc += w3*v3;
  }
  for (; e < e1; ++e) acc += en[e] * xt[(size_t)es[e]*FF + f];
  out[(size_t)n*FF + f] = acc;
}

// h: [N,64]. Wave per node; lane = feature.
__global__ void k_agg_h(const float* __restrict__ h, const int* __restrict__ rp,
                        const int* __restrict__ es, const float* __restrict__ en,
                        const float* __restrict__ invd, float* __restrict__ out){
  int n = blockIdx.x*(blockDim.x >> 6) + (threadIdx.x >> 6);
  if (n >= NN) return;
  int lane = threadIdx.x & 63;
  float acc = invd[n] * h[(size_t)n*HH + lane];
  int e = rp[n], e1 = rp[n+1];
  for (; e + 4 <= e1; e += 4){
    int   s0 = es[e],   s1 = es[e+1], s2 = es[e+2], s3 = es[e+3];
    float w0 = en[e],   w1 = en[e+1], w2 = en[e+2], w3 = en[e+3];
    float v0 = h[(size_t)s0*HH + lane];
    float v1 = h[(size_t)s1*HH + lane];
    float v2 = h[(size_t)s2*HH + lane];
    float v3 = h[(size_t)s3*HH + lane];
    acc += w0*v0; acc += w1*v1; acc += w2*v2; acc += w3*v3;
  }
  for (; e < e1; ++e) acc += en[e] * h[(size_t)es[e]*HH + lane];
  out[(size_t)n*HH + lane] = acc;
}

// ---------------- GEMM: C[M,64] = act(A[M,K] @ W[K,64] + bias) --------------
template<int K, int ROWS, bool RELU>
__launch_bounds__(64)
__global__ void k_gemm(const float* __restrict__ A, const float* __restrict__ W,
                       const float* __restrict__ bias, float* __restrict__ C,
                       int M){
  int col = threadIdx.x;
  float w[K];
  #pragma unroll
  for (int k = 0; k < K; ++k) w[k] = W[(size_t)k*HH + col];
  float b = bias[col];
  int row0 = blockIdx.x*ROWS;
  if (row0 >= M) return;
  float acc[ROWS];
  #pragma unroll
  for (int r = 0; r < ROWS; ++r) acc[r] = b;
  #pragma unroll
  for (int r = 0; r < ROWS; ++r){
    const float* ar = A + (size_t)(row0 + r)*K;
    #pragma unroll
    for (int k = 0; k < K; ++k)
      acc[r] = fmaf(ar[k], w[k], acc[r]);
  }
  #pragma unroll
  for (int r = 0; r < ROWS; ++r){
    float v = acc[r];
    if (RELU) v = fmaxf(v, 0.f);
    C[(size_t)(row0 + r)*HH + col] = v;
  }
}

// ---------------- fused GRU step, v3 ----------------------------------------
// Block = 6 waves (384 thr). Wave wv owns ONE (side,gate): side=wv/3
// (0: h2@Wih^T, 1: hprev@Whh^T), gate=wv%3 (r,z,n). w[64] weights per lane in
// VGPRs (~100 VGPR total -> NO min-waves bound, spill-free). h tile staged in
// LDS, read via same-address broadcast. Gates meet in LDS; flat epilogue.
#define GRB 16
__launch_bounds__(384)
__global__ void k_gruf(const float* __restrict__ h2, const float* __restrict__ hprev,
                       const float* __restrict__ Wih, const float* __restrict__ Whh,
                       const float* __restrict__ bih, const float* __restrict__ bhh,
                       float* __restrict__ hnew, int ntiles){
  __shared__ float sh[2][GRB][64];   // [0]=h2 rows, [1]=hprev rows (8 KB)
  __shared__ float ex[6][GRB][64];   // gate exchange (24 KB)
  int tid = threadIdx.x, wv = tid >> 6, lane = tid & 63;
  int side = wv / 3;
  int gate = wv - side*3;
  const float* Wsel = side ? Whh : Wih;
  float bg = (side ? bhh : bih)[gate*64 + lane];
  float w[64];
  {
    const float* wr = Wsel + (size_t)(gate*64 + lane)*64;
    #pragma unroll
    for (int k = 0; k < 64; k += 4){
      float4 v = *(const float4*)(wr + k);
      w[k]=v.x; w[k+1]=v.y; w[k+2]=v.z; w[k+3]=v.w;
    }
  }

  for (int tile = blockIdx.x; tile < ntiles; tile += gridDim.x){
    int n0 = tile * GRB;
    __syncthreads();   // sh/ex free (previous epilogue done)
    for (int i = tid; i < 2*GRB*16; i += 384){   // 512 float4 = 2 KB/iter
      if (i < GRB*16) ((float4*)sh)[i] = ((const float4*)(h2    + (size_t)n0*64))[i];
      else            ((float4*)sh)[i] = ((const float4*)(hprev + (size_t)n0*64))[i - GRB*16];
    }
    __syncthreads();

    float a[GRB];
    #pragma unroll
    for (int r0 = 0; r0 < GRB; r0 += 4){        // 4 independent FMA chains
      const float* h0 = &sh[side][r0    ][0];
      const float* h1 = &sh[side][r0 + 1][0];
      const float* h2p= &sh[side][r0 + 2][0];
      const float* h3 = &sh[side][r0 + 3][0];
      float s0=0.f, s1=0.f, s2=0.f, s3=0.f;
      #pragma unroll
      for (int k = 0; k < 64; k += 4){
        float4 v0 = *(const float4*)(h0 + k);    // LDS same-addr broadcast
        float4 v1 = *(const float4*)(h1 + k);
        float4 v2 = *(const float4*)(h2p + k);
        float4 v3 = *(const float4*)(h3 + k);
        s0 = fmaf(v0.x, w[k], s0); s0 = fmaf(v0.y, w[k+1], s0);
        s0 = fmaf(v0.z, w[k+2], s0); s0 = fmaf(v0.w, w[k+3], s0);
        s1 = fmaf(v1.x, w[k], s1); s1 = fmaf(v1.y, w[k+1], s1);
        s1 = fmaf(v1.z, w[k+2], s1); s1 = fmaf(v1.w, w[k+3], s1);
        s2 = fmaf(v2.x, w[k], s2); s2 = fmaf(v2.y, w[k+1], s2);
        s2 = fmaf(v2.z, w[k+2], s2); s2 = fmaf(v2.w, w[k+3], s2);
        s3 = fmaf(v3.x, w[k], s3); s3 = fmaf(v3.y, w[k+1], s3);
        s3 = fmaf(v3.z, w[k+2], s3); s3 = fmaf(v3.w, w[k+3], s3);
      }
      a[r0]=s0; a[r0+1]=s1; a[r0+2]=s2; a[r0+3]=s3;
    }
    #pragma unroll
    for (int r = 0; r < GRB; ++r) ex[wv][r][lane] = a[r] + bg;
    __syncthreads();
    for (int i = tid; i < GRB*64; i += 384){
      int row = i >> 6, col = i & 63;
      float ir = ex[0][row][col], iz = ex[1][row][col], in_ = ex[2][row][col];
      float hr = ex[3][row][col], hz = ex[4][row][col], hn  = ex[5][row][col];
      float rg = 1.f/(1.f + expf(-(ir + hr)));
      float zg = 1.f/(1.f + expf(-(iz + hz)));
      float nv = tanhf(in_ + rg*hn);
      float hp = sh[1][row][col];
      hnew[(size_t)(n0 + row)*64 + col] = (1.f - zg)*nv + zg*hp;
    }
  }
}

// ---------------- head: logits = relu(h@Wc1+bc1)@Wc2 + bc2 ----------------
__global__ void k_head(const float* __restrict__ h, const float* __restrict__ Wc1,
                       const float* __restrict__ bc1, const float* __restrict__ Wc2,
                       const float* __restrict__ bc2, float* __restrict__ out){
  __shared__ float w1[64*32];
  __shared__ float w2[32];
  for (int i = threadIdx.x; i < 64*32; i += blockDim.x) w1[i] = Wc1[i];
  if (threadIdx.x < 32) w2[threadIdx.x] = Wc2[threadIdx.x];
  __syncthreads();
  int n = blockIdx.x*blockDim.x + threadIdx.x;
  if (n >= NN) return;
  const float* hr = h + (size_t)n*64;
  float hreg[64];
  #pragma unroll
  for (int k = 0; k < 64; ++k) hreg[k] = hr[k];
  float acc2 = bc2[0];
  #pragma unroll
  for (int c = 0; c < 32; ++c){
    float a = bc1[c];
    #pragma unroll
    for (int k = 0; k < 64; ++k) a = fmaf(hreg[k], w1[k*32 + c], a);
    a = fmaxf(a, 0.f);
    acc2 = fmaf(a, w2[c], acc2);
  }
  out[n] = acc2;
}

// ---------------- launch ----------------
extern "C" void kernel_launch(void* const* d_in, const int* in_sizes, int n_in,
                              void* d_out, int out_size, void* d_ws, size_t ws_size,
                              hipStream_t stream){
  const float* x    = (const float*)d_in[0];
  const int*   ei   = (const int*)  d_in[1];
  const float* W1   = (const float*)d_in[2];
  const float* b1   = (const float*)d_in[3];
  const float* W2   = (const float*)d_in[4];
  const float* b2   = (const float*)d_in[5];
  const float* W_ih = (const float*)d_in[6];
  const float* W_hh = (const float*)d_in[7];
  const float* b_ih = (const float*)d_in[8];
  const float* b_hh = (const float*)d_in[9];
  const float* Wc1  = (const float*)d_in[10];
  const float* bc1  = (const float*)d_in[11];
  const float* Wc2  = (const float*)d_in[12];
  const float* bc2  = (const float*)d_in[13];
  int E = in_sizes[1] / 2;
  const int* src = ei;
  const int* dst = ei + E;

  char* w = (char*)d_ws;
  auto alloc = [&](size_t bytes){ char* p = w; w += align256(bytes); return p; };
  int*   cnt  = (int*)  alloc((size_t)NN*4);
  int*   rp   = (int*)  alloc((size_t)(NN+1)*4);
  int*   cur  = (int*)  alloc((size_t)NN*4);
  float* dinv = (float*)alloc((size_t)NN*4);
  float* invd = (float*)alloc((size_t)NN*4);
  int*   es   = (int*)  alloc((size_t)E*4);
  float* en   = (float*)alloc((size_t)E*4);
  float* U1   = (float*)alloc((size_t)NN*HH*4);   // aggX [N,32] / agg2 [N,64]
  float* U2   = (float*)alloc((size_t)NN*HH*4);   // h1 / h2  [N,64]
  float* hA   = (float*)alloc((size_t)NN*HH*4);
  float* hB   = (float*)alloc((size_t)NN*HH*4);
  if ((size_t)(w - (char*)d_ws) > ws_size) return;   // clean diagnostic fail

  hipMemsetAsync(cnt, 0, (size_t)NN*4, stream);
  hipMemsetAsync(cur, 0, (size_t)NN*4, stream);
  hipMemsetAsync(hA,  0, (size_t)NN*HH*4, stream);   // h0 = 0

  k_count<<<(E+255)/256, 256, 0, stream>>>(dst, E, cnt);
  k_dinv <<<(NN+255)/256, 256, 0, stream>>>(cnt, dinv, invd, NN);
  k_scan <<<1, SCAN_T, 0, stream>>>(cnt, rp, NN);
  k_fill <<<(E+255)/256, 256, 0, stream>>>(src, dst, E, rp, cur, dinv, es, en);

  float* hprev = hA;
  float* hnext = hB;
  for (int t = 0; t < TT; ++t){
    const float* xt = x + (size_t)t*NN*FF;
    // layer 1: aggregate x first ((A X) W == A (X W)), then GEMM 32->64 + relu
    k_agg_x<<<(NN*32 + 255)/256, 256, 0, stream>>>(xt, rp, es, en, invd, U1);
    k_gemm<FF, 16, true><<<(NN + 15)/16, 64, 0, stream>>>(U1, W1, b1, U2, NN);
    // layer 2
    k_agg_h<<<(NN + 3)/4, 256, 0, stream>>>(U2, rp, es, en, invd, U1);
    k_gemm<HH, 16, true><<<(NN + 15)/16, 64, 0, stream>>>(U1, W2, b2, U2, NN);
    // fused GRU step consuming h2 (= U2)
    k_gruf<<<1024, 384, 0, stream>>>(U2, hprev, W_ih, W_hh, b_ih, b_hh, hnext, NN/GRB);
    float* tmp = hprev; hprev = hnext; hnext = tmp;
  }

  // after 12 swaps hprev == hA
  k_head<<<(NN + 255)/256, 256, 0, stream>>>(hprev, Wc1, bc1, Wc2, bc2, (float*)d_out);
}